// Round 8
// baseline (2432.136 us; speedup 1.0000x reference)
//
#include <hip/hip_runtime.h>
#include <cstdint>
#include <cstddef>

typedef _Float16 h2_t __attribute__((ext_vector_type(2)));
typedef unsigned int uint;
typedef unsigned short ushortt;

#define BB 128
#define TT 512

// ---- ws layout (bytes) ----
#define OFF_PHR0 0u           // 18*1024*16 = 294912
#define OFF_PHN0 294912u      // 6*1024*16  = 98304
#define OFF_PHR1 393216u      // 294912
#define OFF_PHN1 688128u      // 98304
#define OFF_PI0  786432u      // 98304
#define OFF_PI1  884736u      // 393216
#define OFF_H2O  1277952u     // 131072
#define OFF_H1   1409024u     // 33554432
#define OFF_GX   34963456u    // 100663296 (end ~135.6 MB)

__device__ __forceinline__ uint pack2(float a, float b){
  h2_t h; h.x = (_Float16)a; h.y = (_Float16)b;
  return __builtin_bit_cast(uint, h);
}
__device__ __forceinline__ float f16f(ushortt s){
  return (float)__builtin_bit_cast(_Float16, s);
}
__device__ __forceinline__ ushortt ff16(float f){
  return __builtin_bit_cast(ushortt, (_Float16)f);
}
__device__ __forceinline__ float dot2(uint w, uint h, float acc){
  return __builtin_amdgcn_fdot2(__builtin_bit_cast(h2_t, w),
                                __builtin_bit_cast(h2_t, h), acc, false);
}
template<int CTRL>
__device__ __forceinline__ float dpp_addf(float x){
  int p = __builtin_amdgcn_update_dpp(0, __float_as_int(x), CTRL, 0xF, 0xF, true);
  return x + __int_as_float(p);
}
template<int CTRL>
__device__ __forceinline__ float dpp_movf(float x){
  return __int_as_float(__builtin_amdgcn_update_dpp(0, __float_as_int(x), CTRL, 0xF, 0xF, true));
}
// sum over 4-lane quads, result in all 4 lanes (verified r4-r7)
__device__ __forceinline__ float red4(float x){
  x = dpp_addf<0xB1>(x); x = dpp_addf<0x4E>(x);
  return x;
}
// sum over 16-lane rows via row_ror DPP, result in all 16 lanes (verified r3)
__device__ __forceinline__ float red16(float x){
  x = dpp_addf<0x128>(x);   // row_ror:8
  x = dpp_addf<0x124>(x);   // row_ror:4
  x = dpp_addf<0x122>(x);   // row_ror:2
  x = dpp_addf<0x121>(x);   // row_ror:1
  return x;
}
__device__ __forceinline__ float sigf(float x){ return 1.0f/(1.0f+__expf(-x)); }
__device__ __forceinline__ float tanhf_(float x){
  x = fminf(15.0f, fmaxf(-15.0f, x));
  float e = __expf(2.0f*x);
  return (e-1.0f)/(e+1.0f);
}
__device__ __forceinline__ float pick4(float a0,float a1,float a2,float a3,int s){
  float x = (s&1)? a1:a0, y = (s&1)? a3:a2;
  return (s&2)? y:x;
}

// =================== prep: pack fp32 weights -> f16 images ===================
// REC org (16-way): q=tid&15 (16-col slice), u=tid>>4 (units 4u..4u+3).
// PHR (RF, 18 uint4/thread): c=rr*2+k2, rr=0..8: rr<4 -> (g0,s=rr); rr<8 -> (g1,s=rr-4);
//   rr=8 -> (g2,s=0). row=g*256+4u+s, dword e = cols 16q+8k2+2e,+1.
// PHN (LDS n-gate, 6 uint4/thread): c=(s-1)*2+k2, s=1..3: row=512+4u+s.
// PI0/PI1: unchanged from r5.
__global__ void prep_kernel(const float* __restrict__ W_ih0, const float* __restrict__ W_hh0,
                            const float* __restrict__ W_ih1, const float* __restrict__ W_hh1,
                            uint* __restrict__ PHR0, uint* __restrict__ PHN0,
                            uint* __restrict__ PHR1, uint* __restrict__ PHN1,
                            uint* __restrict__ PI0, uint* __restrict__ PI1)
{
  int i = blockIdx.x*256 + threadIdx.x;
  if (i < 196608) {
    const int layer = (i >= 98304) ? 1 : 0;
    const float* W = layer ? W_hh1 : W_hh0;
    uint* dstR = layer ? PHR1 : PHR0;
    uint* dstN = layer ? PHN1 : PHN0;
    int j = layer ? (i - 98304) : i;
    if (j < 73728) {
      int e = j&3, u4i = j>>2;
      int tid = u4i & 1023, c = u4i >> 10;    // c 0..17
      int k2 = c & 1, rr = c >> 1;            // rr 0..8
      int g = (rr < 4) ? 0 : ((rr < 8) ? 1 : 2);
      int s = (rr < 8) ? (rr & 3) : 0;
      int qq = tid & 15, uu = tid >> 4;
      int row = g*256 + 4*uu + s, col = 16*qq + 8*k2 + 2*e;
      dstR[j] = pack2(W[row*256+col], W[row*256+col+1]);
    } else {
      int j2 = j - 73728;
      int e = j2&3, u4i = j2>>2;
      int tid = u4i & 1023, c = u4i >> 10;    // c 0..5
      int k2 = c & 1, s = 1 + (c >> 1);
      int qq = tid & 15, uu = tid >> 4;
      int row = 512 + 4*uu + s, col = 16*qq + 8*k2 + 2*e;
      dstN[j2] = pack2(W[row*256+col], W[row*256+col+1]);
    }
  } else if (i < 221184) {
    int j2 = i - 196608;
    int jj = j2 & 255, rc = j2 >> 8;
    int ci = rc & 31, r = rc >> 5;
    PI0[j2] = pack2(W_ih0[(r*256+jj)*64 + 2*ci], W_ih0[(r*256+jj)*64 + 2*ci + 1]);
  } else if (i < 319488) {
    int j3 = i - 221184;
    int tid = j3 & 1023, rc = j3 >> 10;
    int ci = rc & 31, r = rc >> 5;
    int kq = tid & 3, jj = tid >> 2;
    int col = 64*kq + 2*ci;
    PI1[j3] = pack2(W_ih1[(r*256+jj)*256 + col], W_ih1[(r*256+jj)*256 + col + 1]);
  }
}

// =================== GEMM0: gx0 = W_ih0 . x + biases (unchanged from r5) ===================
__global__ __launch_bounds__(512) void gemm0_kernel(
    const float* __restrict__ x, const uint* __restrict__ PI0,
    const float* __restrict__ b_ih0, const float* __restrict__ b_hh0,
    ushortt* __restrict__ gx)
{
  const int blk = blockIdx.x;
  const int b = blk >> 4, t0 = (blk & 15) * 32;
  const int tid = threadIdx.x;
  const int j = tid & 255, th = tid >> 8;
  __shared__ uint xs[32*32];
  {
    float4 v = ((const float4*)x)[((size_t)b*TT + t0 + (tid>>4))*16 + (tid&15)];
    xs[(tid>>4)*32 + (tid&15)*2]     = pack2(v.x, v.y);
    xs[(tid>>4)*32 + (tid&15)*2 + 1] = pack2(v.z, v.w);
  }
  uint w[96];
  #pragma unroll
  for (int rc = 0; rc < 96; ++rc) w[rc] = PI0[rc*256 + j];
  const float br = b_ih0[j] + b_hh0[j];
  const float bz = b_ih0[256+j] + b_hh0[256+j];
  const float bn = b_ih0[512+j];
  __syncthreads();
  ushortt* gout = gx + ((size_t)b*TT + t0 + th*16)*768;
  #pragma unroll 1
  for (int tt = 0; tt < 16; ++tt) {
    const uint* xr = xs + (th*16 + tt)*32;
    float ar=0.f, az=0.f, an=0.f;
    #pragma unroll
    for (int c = 0; c < 32; ++c) {
      uint xv = xr[c];
      ar = dot2(w[c],    xv, ar);
      az = dot2(w[32+c], xv, az);
      an = dot2(w[64+c], xv, an);
    }
    gout[j]     = ff16(ar + br);
    gout[256+j] = ff16(az + bz);
    gout[512+j] = ff16(an + bn);
    gout += 768;
  }
}

// =================== GEMM1: gx1 = W_ih1 . h1 + biases (unchanged from r5) ===================
__global__ __launch_bounds__(1024) void gemm1_kernel(
    const uint* __restrict__ h1, const uint* __restrict__ PI1,
    const float* __restrict__ b_ih1, const float* __restrict__ b_hh1,
    ushortt* __restrict__ gx)
{
  const int blk = blockIdx.x;
  const int b = blk >> 5, t0 = (blk & 31) * 16;
  const int tid = threadIdx.x;
  const int kq = tid & 3, j = tid >> 2;
  __shared__ uint hsT[16*144];
  {
    uint2 v = ((const uint2*)(h1 + ((size_t)b*TT + t0)*128))[tid];
    int f = 2*tid, tp = f>>7, c = f&127, s = c>>2, e = c&3;
    *(uint2*)&hsT[tp*144 + (s + (s>>3))*4 + e] = v;
  }
  uint w[96];
  #pragma unroll
  for (int rc = 0; rc < 96; ++rc) w[rc] = PI1[rc*1024 + tid];
  const float br = b_ih1[j] + b_hh1[j];
  const float bz = b_ih1[256+j] + b_hh1[256+j];
  const float bn = b_ih1[512+j];
  __syncthreads();
  ushortt* gout = gx + ((size_t)b*TT + t0)*768;
  #pragma unroll 1
  for (int tt = 0; tt < 16; ++tt) {
    const uint4* hr = (const uint4*)&hsT[tt*144];
    float ar=0.f, az=0.f, an=0.f;
    #pragma unroll
    for (int i = 0; i < 8; ++i) {
      uint4 hv = hr[9*kq + i];
      ar = dot2(w[4*i],hv.x,ar);    ar = dot2(w[4*i+1],hv.y,ar);
      ar = dot2(w[4*i+2],hv.z,ar);  ar = dot2(w[4*i+3],hv.w,ar);
      az = dot2(w[32+4*i],hv.x,az); az = dot2(w[32+4*i+1],hv.y,az);
      az = dot2(w[32+4*i+2],hv.z,az); az = dot2(w[32+4*i+3],hv.w,az);
      an = dot2(w[64+4*i],hv.x,an); an = dot2(w[64+4*i+1],hv.y,an);
      an = dot2(w[64+4*i+2],hv.z,an); an = dot2(w[64+4*i+3],hv.w,an);
    }
    ar = red4(ar); az = red4(az); an = red4(an);
    if (kq == 0) {
      gout[j]     = ff16(ar + br);
      gout[256+j] = ff16(az + bz);
      gout[512+j] = ff16(an + bn);
    }
    gout += 768;
  }
}

// =================== REC: serial GRU recurrence (r8 redesign) ===================
// 128 blocks x 1024 thr. 16-way k-split: q=tid&15 (cols 16q..16q+15), u=tid>>4
// (units 4u..4u+3). Per-thread weights: 72 uints RF (r,z gates + n s0, pinned)
// + 24 uints LDS (n-gate s1..3, 115 KB, stride 28 -> conflict-free 7t mod 8).
// Reduce: pure-DPP red16 (no ds_swizzle latency in the chain). h in LDS,
// padded u4 -> u4+(u4>>3): reads broadcast across the 4 rows, 2-way max.
// One barrier/step; gx prefetched 2 steps ahead on gate lanes (q<4).
template<bool IS_L0>
__global__ __launch_bounds__(1024, 4) __attribute__((amdgpu_waves_per_eu(4,4)))
void rec_kernel(
    const uint4* __restrict__ PHR, const uint4* __restrict__ PHN,
    const ushortt* __restrict__ GX, const float* __restrict__ b_hh,
    uint* __restrict__ h1, float* __restrict__ h2o)
{
  extern __shared__ uint lds_u[];      // [0,28672): wn; [28672,28960): h dbuf
  const int b = blockIdx.x, tid = threadIdx.x;
  const int q = tid & 15, u = tid >> 4;

  // LDS n-gate weights: 6 uint4 per thread at byte 112*tid (16B-aligned)
  uint4* mywn = (uint4*)(lds_u + 28*tid);
  #pragma unroll
  for (int c = 0; c < 6; ++c) mywn[c] = PHN[c*1024 + tid];

  uint* hbase = lds_u + 28672;         // 2 x 144 uints
  if (tid < 288) hbase[tid] = 0;

  // RF weights (pinned scalars; r7-verified idiom)
  uint w[72];
  #pragma unroll
  for (int c = 0; c < 18; ++c) {
    uint4 v = PHR[c*1024 + tid];
    w[4*c] = v.x; w[4*c+1] = v.y; w[4*c+2] = v.z; w[4*c+3] = v.w;
  }
  #pragma unroll
  for (int c = 0; c < 72; ++c) asm volatile("" : "+v"(w[c]));

  const int j = 4*u + q;               // unit index (meaningful for q<4)
  const bool gl = (q < 4);
  const ushortt* gxp = GX + (size_t)b*TT*768;
  const float bhn = gl ? b_hh[512 + j] : 0.f;
  ushortt gr0=0, gz0=0, gn0=0, gr1=0, gz1=0, gn1=0;
  if (gl) {
    gr0 = gxp[j]; gz0 = gxp[256+j]; gn0 = gxp[512+j];
    gr1 = gxp[768+j]; gz1 = gxp[768+256+j]; gn1 = gxp[768+512+j];
  }
  float h_old = 0.f;
  __syncthreads();
  int cur = 0;
  #pragma unroll 1
  for (int t = 0; t < TT; ++t) {
    const uint4* hb = (const uint4*)(hbase + cur*144);
    const int l0 = 2*q + (q>>2);       // phys u4 of logical 2q
    uint4 h0  = hb[l0];                // cols 16q..16q+7
    uint4 h1v = hb[l0+1];              // cols 16q+8..16q+15
    float aR[4], aZ[4], aN[4];
    #pragma unroll
    for (int s = 0; s < 4; ++s) { aR[s]=0.f; aZ[s]=0.f; aN[s]=0.f; }
    #pragma unroll
    for (int s = 0; s < 4; ++s) {
      aR[s] = dot2(w[(s*2)*4+0],   h0.x, aR[s]); aR[s] = dot2(w[(s*2)*4+1],   h0.y, aR[s]);
      aR[s] = dot2(w[(s*2)*4+2],   h0.z, aR[s]); aR[s] = dot2(w[(s*2)*4+3],   h0.w, aR[s]);
      aR[s] = dot2(w[(s*2+1)*4+0], h1v.x, aR[s]); aR[s] = dot2(w[(s*2+1)*4+1], h1v.y, aR[s]);
      aR[s] = dot2(w[(s*2+1)*4+2], h1v.z, aR[s]); aR[s] = dot2(w[(s*2+1)*4+3], h1v.w, aR[s]);
      aZ[s] = dot2(w[(8+s*2)*4+0], h0.x, aZ[s]); aZ[s] = dot2(w[(8+s*2)*4+1], h0.y, aZ[s]);
      aZ[s] = dot2(w[(8+s*2)*4+2], h0.z, aZ[s]); aZ[s] = dot2(w[(8+s*2)*4+3], h0.w, aZ[s]);
      aZ[s] = dot2(w[(9+s*2)*4+0], h1v.x, aZ[s]); aZ[s] = dot2(w[(9+s*2)*4+1], h1v.y, aZ[s]);
      aZ[s] = dot2(w[(9+s*2)*4+2], h1v.z, aZ[s]); aZ[s] = dot2(w[(9+s*2)*4+3], h1v.w, aZ[s]);
    }
    // n gate: s0 from RF (c=16,17), s1..3 from LDS
    aN[0] = dot2(w[64], h0.x, aN[0]); aN[0] = dot2(w[65], h0.y, aN[0]);
    aN[0] = dot2(w[66], h0.z, aN[0]); aN[0] = dot2(w[67], h0.w, aN[0]);
    aN[0] = dot2(w[68], h1v.x, aN[0]); aN[0] = dot2(w[69], h1v.y, aN[0]);
    aN[0] = dot2(w[70], h1v.z, aN[0]); aN[0] = dot2(w[71], h1v.w, aN[0]);
    #pragma unroll
    for (int s = 1; s < 4; ++s) {
      uint4 wa = mywn[(s-1)*2], wb = mywn[(s-1)*2+1];
      aN[s] = dot2(wa.x, h0.x, aN[s]); aN[s] = dot2(wa.y, h0.y, aN[s]);
      aN[s] = dot2(wa.z, h0.z, aN[s]); aN[s] = dot2(wa.w, h0.w, aN[s]);
      aN[s] = dot2(wb.x, h1v.x, aN[s]); aN[s] = dot2(wb.y, h1v.y, aN[s]);
      aN[s] = dot2(wb.z, h1v.z, aN[s]); aN[s] = dot2(wb.w, h1v.w, aN[s]);
    }
    #pragma unroll
    for (int s = 0; s < 4; ++s) {
      aR[s] = red16(aR[s]); aZ[s] = red16(aZ[s]); aN[s] = red16(aN[s]);
    }
    const int sl = q & 3;
    float R = pick4(aR[0],aR[1],aR[2],aR[3], sl);
    float Z = pick4(aZ[0],aZ[1],aZ[2],aZ[3], sl);
    float N = pick4(aN[0],aN[1],aN[2],aN[3], sl);
    float r = sigf(f16f(gr0) + R);
    float z = sigf(f16f(gz0) + Z);
    float n = tanhf_(f16f(gn0) + r*(N + bhn));
    float hn = z*(h_old - n) + n;
    if (gl) h_old = hn;
    // rotate gx prefetch (2 ahead)
    gr0 = gr1; gz0 = gz1; gn0 = gn1;
    if (gl && t + 2 < TT) {
      const ushortt* p = gxp + (size_t)(t+2)*768;
      gr1 = p[j]; gz1 = p[256+j]; gn1 = p[512+j];
    }
    // publish h: lanes 0/2 of each 16-row write packed pairs
    float hx = dpp_movf<0xB1>(hn);     // partner lane q^1
    uint hv2 = pack2(hn, hx);          // even q: units (4u+q, 4u+q+1)
    if ((q & 1) == 0 && q < 4) {
      const int jj = 2*u + (q>>1);     // h uint index
      const int u4 = jj >> 2, e = jj & 3;
      uint* dst = hbase + (cur^1)*144;
      dst[4*(u4 + (u4>>3)) + e] = hv2;
      if (IS_L0) h1[((size_t)b*TT + t)*128 + jj] = hv2;
    }
    if (!IS_L0 && t == TT-1 && gl) h2o[b*256 + j] = hn;
    __syncthreads();
    cur ^= 1;
  }
}

// =================== MLP head (unchanged) ===================
__global__ __launch_bounds__(128) void mlp_kernel(
    const float* __restrict__ h2, const float* __restrict__ W1,
    const float* __restrict__ b1, const float* __restrict__ W2,
    const float* __restrict__ b2, float* __restrict__ out)
{
  __shared__ float hls[256];
  __shared__ float red[128];
  const int b = blockIdx.x, tid = threadIdx.x;
  if (tid < 64) ((float4*)hls)[tid] = ((const float4*)(h2 + (size_t)b*256))[tid];
  __syncthreads();
  float acc = b1[tid];
  const float4* w4 = (const float4*)(W1 + (size_t)tid*256);
  const float4* h4 = (const float4*)hls;
  #pragma unroll 8
  for (int k = 0; k < 64; ++k) {
    float4 w = w4[k]; float4 h = h4[k];
    acc = fmaf(w.x,h.x,acc); acc = fmaf(w.y,h.y,acc);
    acc = fmaf(w.z,h.z,acc); acc = fmaf(w.w,h.w,acc);
  }
  red[tid] = fmaxf(acc, 0.0f) * W2[tid];
  __syncthreads();
  for (int s = 64; s > 0; s >>= 1) {
    if (tid < s) red[tid] += red[tid + s];
    __syncthreads();
  }
  if (tid == 0) out[b] = red[0] + b2[0];
}

extern "C" void kernel_launch(void* const* d_in, const int* in_sizes, int n_in,
                              void* d_out, int out_size, void* d_ws, size_t ws_size,
                              hipStream_t stream)
{
  const float* x     = (const float*)d_in[0];
  const float* W_ih0 = (const float*)d_in[1];
  const float* W_hh0 = (const float*)d_in[2];
  const float* b_ih0 = (const float*)d_in[3];
  const float* b_hh0 = (const float*)d_in[4];
  const float* W_ih1 = (const float*)d_in[5];
  const float* W_hh1 = (const float*)d_in[6];
  const float* b_ih1 = (const float*)d_in[7];
  const float* b_hh1 = (const float*)d_in[8];
  const float* W1    = (const float*)d_in[9];
  const float* b1    = (const float*)d_in[10];
  const float* W2    = (const float*)d_in[11];
  const float* b2    = (const float*)d_in[12];

  char* ws = (char*)d_ws;
  uint*    PHR0 = (uint*)(ws + OFF_PHR0);
  uint*    PHN0 = (uint*)(ws + OFF_PHN0);
  uint*    PHR1 = (uint*)(ws + OFF_PHR1);
  uint*    PHN1 = (uint*)(ws + OFF_PHN1);
  uint*    PI0  = (uint*)(ws + OFF_PI0);
  uint*    PI1  = (uint*)(ws + OFF_PI1);
  float*   H2O  = (float*)(ws + OFF_H2O);
  uint*    H1   = (uint*)(ws + OFF_H1);
  ushortt* GX   = (ushortt*)(ws + OFF_GX);

  const int rec_lds = 28960 * 4;   // 115840 B
  (void)hipFuncSetAttribute(reinterpret_cast<const void*>(&rec_kernel<true>),
                            hipFuncAttributeMaxDynamicSharedMemorySize, rec_lds);
  (void)hipFuncSetAttribute(reinterpret_cast<const void*>(&rec_kernel<false>),
                            hipFuncAttributeMaxDynamicSharedMemorySize, rec_lds);

  prep_kernel<<<1248, 256, 0, stream>>>(W_ih0, W_hh0, W_ih1, W_hh1,
                                        PHR0, PHN0, PHR1, PHN1, PI0, PI1);
  gemm0_kernel<<<2048, 512, 0, stream>>>(x, PI0, b_ih0, b_hh0, GX);
  rec_kernel<true><<<BB, 1024, rec_lds, stream>>>((const uint4*)PHR0, (const uint4*)PHN0,
                                                  GX, b_hh0, H1, nullptr);
  gemm1_kernel<<<4096, 1024, 0, stream>>>(H1, PI1, b_ih1, b_hh1, GX);
  rec_kernel<false><<<BB, 1024, rec_lds, stream>>>((const uint4*)PHR1, (const uint4*)PHN1,
                                                   GX, b_hh1, nullptr, H2O);
  mlp_kernel<<<BB, 128, 0, stream>>>(H2O, W1, b1, W2, b2, (float*)d_out);
}

// Round 9
// 2153.388 us; speedup vs baseline: 1.1294x; 1.1294x over previous
//
#include <hip/hip_runtime.h>
#include <cstdint>
#include <cstddef>

typedef _Float16 h2_t __attribute__((ext_vector_type(2)));
typedef unsigned int uint;
typedef unsigned short ushortt;

#define BB 128
#define TT 512

// ---- ws layout (bytes) ----
#define OFF_PRF0 0u           // 6*1024*16  = 98304   (RF image, layer0)
#define OFF_PLD0 98304u       // 9*1024*16  = 147456  (LDS image)
#define OFF_PST0 245760u      // 9*1024*16  = 147456  (L2-streamed image)
#define OFF_PRF1 393216u      // 98304
#define OFF_PLD1 491520u      // 147456
#define OFF_PST1 638976u      // 147456
#define OFF_PI0  786432u      // 98304
#define OFF_PI1  884736u      // 393216
#define OFF_H2O  1277952u     // 131072
#define OFF_H1   1409024u     // 33554432
#define OFF_GX   34963456u    // 100663296 (end ~135.6 MB)

__device__ __forceinline__ uint pack2(float a, float b){
  h2_t h; h.x = (_Float16)a; h.y = (_Float16)b;
  return __builtin_bit_cast(uint, h);
}
__device__ __forceinline__ float f16f(ushortt s){
  return (float)__builtin_bit_cast(_Float16, s);
}
__device__ __forceinline__ ushortt ff16(float f){
  return __builtin_bit_cast(ushortt, (_Float16)f);
}
__device__ __forceinline__ float dot2(uint w, uint h, float acc){
  return __builtin_amdgcn_fdot2(__builtin_bit_cast(h2_t, w),
                                __builtin_bit_cast(h2_t, h), acc, false);
}
__device__ __forceinline__ float d16(uint4 w, uint4 h, float a){
  a = dot2(w.x,h.x,a); a = dot2(w.y,h.y,a);
  a = dot2(w.z,h.z,a); a = dot2(w.w,h.w,a);
  return a;
}
template<int CTRL>
__device__ __forceinline__ float dpp_addf(float x){
  int p = __builtin_amdgcn_update_dpp(0, __float_as_int(x), CTRL, 0xF, 0xF, true);
  return x + __int_as_float(p);
}
template<int CTRL>
__device__ __forceinline__ float dpp_movf(float x){
  return __int_as_float(__builtin_amdgcn_update_dpp(0, __float_as_int(x), CTRL, 0xF, 0xF, true));
}
// sum over 4-lane quads, result in all 4 lanes (verified r4-r8)
__device__ __forceinline__ float red4(float x){
  x = dpp_addf<0xB1>(x); x = dpp_addf<0x4E>(x);
  return x;
}
// sum over 8-lane groups (q = lane&7), result in all 8 lanes (verified r1..r7)
__device__ __forceinline__ float red8(float x){
  x = dpp_addf<0xB1>(x); x = dpp_addf<0x4E>(x);
  int y = __builtin_amdgcn_ds_swizzle(__float_as_int(x), 0x101F);
  return x + __int_as_float(y);
}
__device__ __forceinline__ float sigf(float x){ return 1.0f/(1.0f+__expf(-x)); }
__device__ __forceinline__ float tanhf_(float x){
  x = fminf(15.0f, fmaxf(-15.0f, x));
  float e = __expf(2.0f*x);
  return (e-1.0f)/(e+1.0f);
}

// =================== prep: pack fp32 weights -> f16 images ===================
// REC org (r5/r7-verified): thread (q=tid&7, u=tid>>3, units 2u,2u+1);
// chunk c = r*4+k4, r = g*2+s: row = g*256+2u+s, dword e = cols 32q+8k4+2e,+1.
// Split by c: c<6 -> PRF (register-resident), c<15 -> PLD (LDS), else PST (L2 stream).
// PI0/PI1: unchanged from r5.
__global__ void prep_kernel(const float* __restrict__ W_ih0, const float* __restrict__ W_hh0,
                            const float* __restrict__ W_ih1, const float* __restrict__ W_hh1,
                            uint* __restrict__ PRF0, uint* __restrict__ PLD0, uint* __restrict__ PST0,
                            uint* __restrict__ PRF1, uint* __restrict__ PLD1, uint* __restrict__ PST1,
                            uint* __restrict__ PI0, uint* __restrict__ PI1)
{
  int i = blockIdx.x*256 + threadIdx.x;
  if (i < 196608) {
    const int layer = (i >= 98304) ? 1 : 0;
    const float* W = layer ? W_hh1 : W_hh0;
    int j = layer ? (i - 98304) : i;
    int e = j&3, r2 = j>>2;
    int tid = r2 & 1023, c = r2 >> 10;
    int q = tid&7, u = tid>>3, k4 = c&3, r = c>>2;
    int g = r>>1, s = r&1;
    int row = g*256 + 2*u + s, col = 32*q + 8*k4 + 2*e;
    uint val = pack2(W[row*256+col], W[row*256+col+1]);
    if (c < 6)       (layer ? PRF1 : PRF0)[j]         = val;
    else if (c < 15) (layer ? PLD1 : PLD0)[j - 24576] = val;
    else             (layer ? PST1 : PST0)[j - 61440] = val;
  } else if (i < 221184) {
    int j2 = i - 196608;
    int jj = j2 & 255, rc = j2 >> 8;
    int ci = rc & 31, r = rc >> 5;
    PI0[j2] = pack2(W_ih0[(r*256+jj)*64 + 2*ci], W_ih0[(r*256+jj)*64 + 2*ci + 1]);
  } else if (i < 319488) {
    int j3 = i - 221184;
    int tid = j3 & 1023, rc = j3 >> 10;
    int ci = rc & 31, r = rc >> 5;
    int kq = tid & 3, jj = tid >> 2;
    int col = 64*kq + 2*ci;
    PI1[j3] = pack2(W_ih1[(r*256+jj)*256 + col], W_ih1[(r*256+jj)*256 + col + 1]);
  }
}

// =================== GEMM0: gx0 = W_ih0 . x + biases (unchanged from r5) ===================
__global__ __launch_bounds__(512) void gemm0_kernel(
    const float* __restrict__ x, const uint* __restrict__ PI0,
    const float* __restrict__ b_ih0, const float* __restrict__ b_hh0,
    ushortt* __restrict__ gx)
{
  const int blk = blockIdx.x;
  const int b = blk >> 4, t0 = (blk & 15) * 32;
  const int tid = threadIdx.x;
  const int j = tid & 255, th = tid >> 8;
  __shared__ uint xs[32*32];
  {
    float4 v = ((const float4*)x)[((size_t)b*TT + t0 + (tid>>4))*16 + (tid&15)];
    xs[(tid>>4)*32 + (tid&15)*2]     = pack2(v.x, v.y);
    xs[(tid>>4)*32 + (tid&15)*2 + 1] = pack2(v.z, v.w);
  }
  uint w[96];
  #pragma unroll
  for (int rc = 0; rc < 96; ++rc) w[rc] = PI0[rc*256 + j];
  const float br = b_ih0[j] + b_hh0[j];
  const float bz = b_ih0[256+j] + b_hh0[256+j];
  const float bn = b_ih0[512+j];
  __syncthreads();
  ushortt* gout = gx + ((size_t)b*TT + t0 + th*16)*768;
  #pragma unroll 1
  for (int tt = 0; tt < 16; ++tt) {
    const uint* xr = xs + (th*16 + tt)*32;
    float ar=0.f, az=0.f, an=0.f;
    #pragma unroll
    for (int c = 0; c < 32; ++c) {
      uint xv = xr[c];
      ar = dot2(w[c],    xv, ar);
      az = dot2(w[32+c], xv, az);
      an = dot2(w[64+c], xv, an);
    }
    gout[j]     = ff16(ar + br);
    gout[256+j] = ff16(az + bz);
    gout[512+j] = ff16(an + bn);
    gout += 768;
  }
}

// =================== GEMM1: gx1 = W_ih1 . h1 + biases (unchanged from r5) ===================
__global__ __launch_bounds__(1024) void gemm1_kernel(
    const uint* __restrict__ h1, const uint* __restrict__ PI1,
    const float* __restrict__ b_ih1, const float* __restrict__ b_hh1,
    ushortt* __restrict__ gx)
{
  const int blk = blockIdx.x;
  const int b = blk >> 5, t0 = (blk & 31) * 16;
  const int tid = threadIdx.x;
  const int kq = tid & 3, j = tid >> 2;
  __shared__ uint hsT[16*144];
  {
    uint2 v = ((const uint2*)(h1 + ((size_t)b*TT + t0)*128))[tid];
    int f = 2*tid, tp = f>>7, c = f&127, s = c>>2, e = c&3;
    *(uint2*)&hsT[tp*144 + (s + (s>>3))*4 + e] = v;
  }
  uint w[96];
  #pragma unroll
  for (int rc = 0; rc < 96; ++rc) w[rc] = PI1[rc*1024 + tid];
  const float br = b_ih1[j] + b_hh1[j];
  const float bz = b_ih1[256+j] + b_hh1[256+j];
  const float bn = b_ih1[512+j];
  __syncthreads();
  ushortt* gout = gx + ((size_t)b*TT + t0)*768;
  #pragma unroll 1
  for (int tt = 0; tt < 16; ++tt) {
    const uint4* hr = (const uint4*)&hsT[tt*144];
    float ar=0.f, az=0.f, an=0.f;
    #pragma unroll
    for (int i = 0; i < 8; ++i) {
      uint4 hv = hr[9*kq + i];
      ar = dot2(w[4*i],hv.x,ar);    ar = dot2(w[4*i+1],hv.y,ar);
      ar = dot2(w[4*i+2],hv.z,ar);  ar = dot2(w[4*i+3],hv.w,ar);
      az = dot2(w[32+4*i],hv.x,az); az = dot2(w[32+4*i+1],hv.y,az);
      az = dot2(w[32+4*i+2],hv.z,az); az = dot2(w[32+4*i+3],hv.w,az);
      an = dot2(w[64+4*i],hv.x,an); an = dot2(w[64+4*i+1],hv.y,an);
      an = dot2(w[64+4*i+2],hv.z,an); an = dot2(w[64+4*i+3],hv.w,an);
    }
    ar = red4(ar); az = red4(az); an = red4(an);
    if (kq == 0) {
      gout[j]     = ff16(ar + br);
      gout[256+j] = ff16(az + bz);
      gout[512+j] = ff16(an + bn);
    }
    gout += 768;
  }
}

// =================== REC: serial GRU recurrence (r9: 3-pipe weight split) ===================
// r7 structure (8-way k-split, red8, padded h dbuf, 2-ahead gx prefetch) with the
// 24 weight-quads/thread split across three concurrent pipes:
//   c=0..5   -> RF, pinned scalars (96 KB/CU; small enough to actually stick)
//   c=6..14  -> LDS, per-thread-private, stride-9 quads (147 KB; optimal 128 B/cyc)
//   c=15..23 -> streamed from L2 each step (147 KB/step; 16 blk/XCD x 147 KB = 2.4 MB
//               fits per-XCD L2, unlike r7's 6.3 MB full image -> no HBM re-fetch).
// Streamed quads consumed LAST in the accumulation chain for load slack.
template<bool IS_L0>
__global__ __launch_bounds__(1024) void rec_kernel(
    const uint4* __restrict__ PRF, const uint4* __restrict__ PLD,
    const uint4* __restrict__ PST,
    const ushortt* __restrict__ GX, const float* __restrict__ b_hh,
    uint* __restrict__ h1, float* __restrict__ h2o)
{
  extern __shared__ uint lds_u[];           // [0,36864): ldsw quads; [36864,37184): h dbuf
  uint4* ldsw  = (uint4*)lds_u;             // [1024][9] per-thread-private
  uint*  hbase = lds_u + 36864;             // 2 x 160 uints (padded phys = c + 4*(c>>4))
  const int b = blockIdx.x, tid = threadIdx.x;
  const int q = tid & 7, u = tid >> 3;

  #pragma unroll
  for (int i = 0; i < 9; ++i) ldsw[tid*9 + i] = PLD[i*1024 + tid];
  if (tid < 320) hbase[tid] = 0;

  uint w[24];
  #pragma unroll
  for (int c = 0; c < 6; ++c) {
    uint4 v = PRF[c*1024 + tid];
    w[4*c] = v.x; w[4*c+1] = v.y; w[4*c+2] = v.z; w[4*c+3] = v.w;
  }
  #pragma unroll
  for (int c = 0; c < 24; ++c) asm volatile("" : "+v"(w[c]));  // r7-verified pin idiom

  const int j = 2*u + q;                // unit index (valid for q<2)
  const bool gl = (q < 2);
  const ushortt* gxp = GX + (size_t)b*TT*768;
  const float bhn = gl ? b_hh[512 + j] : 0.f;
  ushortt gr0=0, gz0=0, gn0=0, gr1=0, gz1=0, gn1=0;
  if (gl) {
    gr0 = gxp[j]; gz0 = gxp[256+j]; gn0 = gxp[512+j];
    gr1 = gxp[768+j]; gz1 = gxp[768+256+j]; gn1 = gxp[768+512+j];
  }
  float h_old = 0.f;
  __syncthreads();
  int cur = 0;
  #pragma unroll 1
  for (int t = 0; t < TT; ++t) {
    // issue the streamed-weight loads first (used last -> max slack)
    uint4 ws[9];
    #pragma unroll
    for (int i = 0; i < 9; ++i) ws[i] = PST[i*1024 + tid];

    const uint4* hr = (const uint4*)&hbase[cur*160];
    uint4 hk[4];
    #pragma unroll
    for (int k4 = 0; k4 < 4; ++k4) hk[k4] = hr[5*q + k4];  // phys 20q+4k4, conflict-free (r7)

    float a[6] = {0.f,0.f,0.f,0.f,0.f,0.f};   // a[r], r=g*2+s: r/z/n gates x units 2u,2u+1
    // RF: c = 0..5
    #pragma unroll
    for (int c = 0; c < 6; ++c) {
      uint4 wv; wv.x = w[4*c]; wv.y = w[4*c+1]; wv.z = w[4*c+2]; wv.w = w[4*c+3];
      a[c>>2] = d16(wv, hk[c&3], a[c>>2]);
    }
    // LDS: c = 6..14
    #pragma unroll
    for (int i = 0; i < 9; ++i) {
      const int c = 6 + i;
      a[c>>2] = d16(ldsw[tid*9 + i], hk[c&3], a[c>>2]);
    }
    // stream: c = 15..23
    #pragma unroll
    for (int i = 0; i < 9; ++i) {
      const int c = 15 + i;
      a[c>>2] = d16(ws[i], hk[c&3], a[c>>2]);
    }
    #pragma unroll
    for (int r6 = 0; r6 < 6; ++r6) a[r6] = red8(a[r6]);

    const bool odd = (q & 1);
    float Sr = odd ? a[1] : a[0];
    float Sz = odd ? a[3] : a[2];
    float Sn = odd ? a[5] : a[4];
    float r = sigf(f16f(gr0) + Sr);
    float z = sigf(f16f(gz0) + Sz);
    float n = tanhf_(f16f(gn0) + r*(Sn + bhn));
    float hn = z*(h_old - n) + n;
    if (gl) h_old = hn;
    gr0 = gr1; gz0 = gz1; gn0 = gn1;
    if (gl && t + 2 < TT) {
      const ushortt* p = gxp + (size_t)(t+2)*768;
      gr1 = p[j]; gz1 = p[256+j]; gn1 = p[512+j];
    }
    float hx = dpp_movf<0xB1>(hn);
    uint hv2 = pack2(hn, hx);
    if (q == 0) {
      hbase[(cur^1)*160 + u + 4*(u>>4)] = hv2;
      if (IS_L0) h1[((size_t)b*TT + t)*128 + u] = hv2;
    }
    if (!IS_L0 && t == TT-1 && gl) h2o[b*256 + j] = hn;
    __syncthreads();
    cur ^= 1;
  }
}

// =================== MLP head (unchanged) ===================
__global__ __launch_bounds__(128) void mlp_kernel(
    const float* __restrict__ h2, const float* __restrict__ W1,
    const float* __restrict__ b1, const float* __restrict__ W2,
    const float* __restrict__ b2, float* __restrict__ out)
{
  __shared__ float hls[256];
  __shared__ float red[128];
  const int b = blockIdx.x, tid = threadIdx.x;
  if (tid < 64) ((float4*)hls)[tid] = ((const float4*)(h2 + (size_t)b*256))[tid];
  __syncthreads();
  float acc = b1[tid];
  const float4* w4 = (const float4*)(W1 + (size_t)tid*256);
  const float4* h4 = (const float4*)hls;
  #pragma unroll 8
  for (int k = 0; k < 64; ++k) {
    float4 w = w4[k]; float4 h = h4[k];
    acc = fmaf(w.x,h.x,acc); acc = fmaf(w.y,h.y,acc);
    acc = fmaf(w.z,h.z,acc); acc = fmaf(w.w,h.w,acc);
  }
  red[tid] = fmaxf(acc, 0.0f) * W2[tid];
  __syncthreads();
  for (int s = 64; s > 0; s >>= 1) {
    if (tid < s) red[tid] += red[tid + s];
    __syncthreads();
  }
  if (tid == 0) out[b] = red[0] + b2[0];
}

extern "C" void kernel_launch(void* const* d_in, const int* in_sizes, int n_in,
                              void* d_out, int out_size, void* d_ws, size_t ws_size,
                              hipStream_t stream)
{
  const float* x     = (const float*)d_in[0];
  const float* W_ih0 = (const float*)d_in[1];
  const float* W_hh0 = (const float*)d_in[2];
  const float* b_ih0 = (const float*)d_in[3];
  const float* b_hh0 = (const float*)d_in[4];
  const float* W_ih1 = (const float*)d_in[5];
  const float* W_hh1 = (const float*)d_in[6];
  const float* b_ih1 = (const float*)d_in[7];
  const float* b_hh1 = (const float*)d_in[8];
  const float* W1    = (const float*)d_in[9];
  const float* b1    = (const float*)d_in[10];
  const float* W2    = (const float*)d_in[11];
  const float* b2    = (const float*)d_in[12];

  char* ws = (char*)d_ws;
  uint*    PRF0 = (uint*)(ws + OFF_PRF0);
  uint*    PLD0 = (uint*)(ws + OFF_PLD0);
  uint*    PST0 = (uint*)(ws + OFF_PST0);
  uint*    PRF1 = (uint*)(ws + OFF_PRF1);
  uint*    PLD1 = (uint*)(ws + OFF_PLD1);
  uint*    PST1 = (uint*)(ws + OFF_PST1);
  uint*    PI0  = (uint*)(ws + OFF_PI0);
  uint*    PI1  = (uint*)(ws + OFF_PI1);
  float*   H2O  = (float*)(ws + OFF_H2O);
  uint*    H1   = (uint*)(ws + OFF_H1);
  ushortt* GX   = (ushortt*)(ws + OFF_GX);

  const int rec_lds = 36864*4 + 320*4;   // 148736 B
  (void)hipFuncSetAttribute(reinterpret_cast<const void*>(&rec_kernel<true>),
                            hipFuncAttributeMaxDynamicSharedMemorySize, rec_lds);
  (void)hipFuncSetAttribute(reinterpret_cast<const void*>(&rec_kernel<false>),
                            hipFuncAttributeMaxDynamicSharedMemorySize, rec_lds);

  prep_kernel<<<1248, 256, 0, stream>>>(W_ih0, W_hh0, W_ih1, W_hh1,
                                        PRF0, PLD0, PST0, PRF1, PLD1, PST1, PI0, PI1);
  gemm0_kernel<<<2048, 512, 0, stream>>>(x, PI0, b_ih0, b_hh0, GX);
  rec_kernel<true><<<BB, 1024, rec_lds, stream>>>((const uint4*)PRF0, (const uint4*)PLD0,
                                                  (const uint4*)PST0, GX, b_hh0, H1, nullptr);
  gemm1_kernel<<<4096, 1024, 0, stream>>>(H1, PI1, b_ih1, b_hh1, GX);
  rec_kernel<false><<<BB, 1024, rec_lds, stream>>>((const uint4*)PRF1, (const uint4*)PLD1,
                                                   (const uint4*)PST1, GX, b_hh1, nullptr, H2O);
  mlp_kernel<<<BB, 128, 0, stream>>>(H2O, W1, b1, W2, b2, (float*)d_out);
}